// Round 15
// baseline (2051.193 us; speedup 1.0000x reference)
//
#include <hip/hip_runtime.h>
#include <stdint.h>

#define LAYERS 4
#define BB 16
#define TT 512
#define CC 1024
#define HH 16
#define DD 64
#define VV 32000
#define MM (BB*TT)   // 8192 rows

typedef __attribute__((ext_vector_type(8))) short bf16x8;
typedef __attribute__((ext_vector_type(4))) float f32x4;
typedef __attribute__((ext_vector_type(16))) float f32x16;

__device__ __forceinline__ unsigned short f2b(float f) {
  union { float f; unsigned int u; } v; v.f = f;
  unsigned int r = v.u + 0x7FFFu + ((v.u >> 16) & 1u);
  return (unsigned short)(r >> 16);
}
__device__ __forceinline__ float blo(unsigned int u) {
  union { unsigned int x; float f; } v; v.x = u << 16; return v.f;
}
__device__ __forceinline__ float bhi(unsigned int u) {
  union { unsigned int x; float f; } v; v.x = u & 0xFFFF0000u; return v.f;
}
__device__ __forceinline__ uint32_t pkbf(float lo, float hi) {
  uint32_t d; asm("v_cvt_pk_bf16_f32 %0, %1, %2" : "=v"(d) : "v"(lo), "v"(hi)); return d;
}
__device__ __forceinline__ float ex2(float x) {
  float r; asm("v_exp_f32 %0, %1" : "=v"(r) : "v"(x)); return r;
}
__device__ __forceinline__ void gload16(const unsigned short* g, const unsigned short* lds) {
  __builtin_amdgcn_global_load_lds((const __attribute__((address_space(1))) void*)g,
                                   (__attribute__((address_space(3))) void*)lds, 16, 0, 0);
}

// ---------------- fused weight fp32 -> bf16 (all 4 weight tensors, 1 launch) ----------------
__global__ __launch_bounds__(256) void cvt4_kernel(
    const float* __restrict__ a, const float* __restrict__ b,
    const float* __restrict__ c, const float* __restrict__ d,
    unsigned short* __restrict__ wa, unsigned short* __restrict__ wb,
    unsigned short* __restrict__ wc, unsigned short* __restrict__ wd) {
  const int nA = LAYERS * 3 * CC * CC / 4;
  const int nR = LAYERS * CC * CC / 4;
  int i = blockIdx.x * 256 + threadIdx.x;
  const float* src; unsigned short* dst; int off;
  if (i < nA)               { src = a; dst = wa; off = i; }
  else if (i < nA + nR)     { src = b; dst = wb; off = i - nA; }
  else if (i < nA + 2 * nR) { src = c; dst = wc; off = i - nA - nR; }
  else                      { src = d; dst = wd; off = i - nA - 2 * nR; }
  float4 v = ((const float4*)src)[off];
  ushort4 o; o.x = f2b(v.x); o.y = f2b(v.y); o.z = f2b(v.z); o.w = f2b(v.w);
  ((ushort4*)dst)[off] = o;
}

// ---------------- embedding: x = emb[Xm] + pos ----------------
__global__ __launch_bounds__(256) void embed_kernel(const int* __restrict__ X, const int* __restrict__ S,
    const float* __restrict__ emb, const float* __restrict__ pos,
    float* __restrict__ x, unsigned short* __restrict__ xb) {
  int bt = blockIdx.x; int tid = threadIdx.x;
  int t = bt & (TT - 1);
  int tok = S[bt] ? X[bt] : VV;
  float4 e = ((const float4*)(emb + (size_t)tok * CC))[tid];
  float4 p = ((const float4*)(pos + (size_t)t * CC))[tid];
  float4 r; r.x = e.x + p.x; r.y = e.y + p.y; r.z = e.z + p.z; r.w = e.w + p.w;
  ((float4*)(x + (size_t)bt * CC))[tid] = r;
  ushort4 ub; ub.x = f2b(r.x); ub.y = f2b(r.y); ub.z = f2b(r.z); ub.w = f2b(r.w);
  ((ushort4*)(xb + (size_t)bt * CC))[tid] = ub;
}

// ---------------- GEMM v8 (R10-verified): BK=32, double-buffer, multi-block/CU ----------------
// WPE = launch_bounds min-waves-per-EU. BM=256: WPE=6 -> 24 waves/CU = 3 blocks/CU
// (LDS 48KB x3 = 144 <= 160; VGPR cap 85 >> 36 measured -- no spill). BM=128: WPE=4 (2 blk, at
// its 30% LDS ceiling already). LDS model: BM=128 ceiling 30% MfmaUtil (measured 29.8, AT it);
// BM=256 ceiling 45% (measured 28) -- extra waves fill convoy bubbles.
template<int EPI, int BM, int WPE>
__global__ __launch_bounds__(512, WPE) void gemm8_kernel(
    const unsigned short* __restrict__ A,
    const unsigned short* __restrict__ W,
    float* __restrict__ xres,
    unsigned short* __restrict__ outb,
    const float* __restrict__ bias,
    int N, int nbx) {
  constexpr int NA = BM / 128;
  constexpr int MI = BM / 64;
  constexpr int BUFS = (BM + 128) * 32;
  extern __shared__ unsigned short lds[];
  const int K = 1024;
  const int tid = threadIdx.x;
  const int wv = tid >> 6, ln = tid & 63;
  const int g = ln >> 4, rr = ln & 15;
  const int wm = wv >> 1, wn = wv & 1;

  const int nwg = gridDim.x;
  const int bid = blockIdx.x;
  const int swz = (bid & 7) * (nwg >> 3) + (bid >> 3);
  const int by = swz / nbx, bx = swz - by * nbx;
  const int brow = by * BM, bcol = bx * 128;

  const unsigned short* asrc[NA];
  #pragma unroll
  for (int rd = 0; rd < NA; ++rd) {
    int p = rd * 512 + tid;
    int row = p >> 2, gg = p & 3;
    asrc[rd] = A + (size_t)(brow + row) * K + (gg ^ ((row >> 1) & 3)) * 8;
  }
  const unsigned short* bsrc;
  {
    int row = tid >> 2, gg = tid & 3;
    bsrc = W + (size_t)(bcol + row) * K + (gg ^ ((row >> 1) & 3)) * 8;
  }

  auto stage = [&](int tile, int buf) {
    unsigned short* Aba = lds + buf * BUFS;
    unsigned short* Bba = Aba + BM * 32;
    int ko = tile * 32;
    #pragma unroll
    for (int rd = 0; rd < NA; ++rd)
      gload16(asrc[rd] + ko, Aba + (rd * 512 + wv * 64) * 8);
    gload16(bsrc + ko, Bba + (wv * 64) * 8);
  };

  f32x4 acc[MI][4];
  #pragma unroll
  for (int i = 0; i < MI; ++i)
    #pragma unroll
    for (int j = 0; j < 4; ++j)
      acc[i][j] = (f32x4){0.f, 0.f, 0.f, 0.f};

  stage(0, 0);

  const int chx = (g ^ ((rr >> 1) & 3)) * 8;
  for (int t = 0; t < 32; ++t) {
    if (t < 31) {
      stage(t + 1, (t + 1) & 1);
      asm volatile("s_waitcnt vmcnt(%0)" :: "i"(NA + 1) : "memory");
    } else {
      asm volatile("s_waitcnt vmcnt(0)" ::: "memory");
    }
    __builtin_amdgcn_s_barrier();
    __builtin_amdgcn_sched_barrier(0);

    const unsigned short* Aba = lds + (t & 1) * BUFS;
    const unsigned short* Bba = Aba + BM * 32;
    bf16x8 av[MI], bv[4];
    #pragma unroll
    for (int i = 0; i < MI; ++i)
      av[i] = *(const bf16x8*)(Aba + (wm * (BM / 4) + i * 16 + rr) * 32 + chx);
    #pragma unroll
    for (int j = 0; j < 4; ++j)
      bv[j] = *(const bf16x8*)(Bba + (wn * 64 + j * 16 + rr) * 32 + chx);

    __builtin_amdgcn_s_setprio(1);
    #pragma unroll
    for (int i = 0; i < MI; ++i)
      #pragma unroll
      for (int j = 0; j < 4; ++j)
        acc[i][j] = __builtin_amdgcn_mfma_f32_16x16x32_bf16(av[i], bv[j], acc[i][j], 0, 0, 0);
    __builtin_amdgcn_s_setprio(0);
    __builtin_amdgcn_sched_barrier(0);
    __builtin_amdgcn_s_barrier();
  }

  #pragma unroll
  for (int i = 0; i < MI; ++i) {
    #pragma unroll
    for (int j = 0; j < 4; ++j) {
      #pragma unroll
      for (int q = 0; q < 4; ++q) {
        int rowg = brow + wm * (BM / 4) + i * 16 + g * 4 + q;
        int colg = bcol + wn * 64 + j * 16 + rr;
        size_t off = (size_t)rowg * N + colg;
        float vacc = acc[i][j][q];
        if (EPI == 0) {
          outb[off] = f2b(vacc);
        } else if (EPI == 1) {
          float nx = xres[off] + vacc;
          xres[off] = nx; outb[off] = f2b(nx);
        } else if (EPI == 2) {
          float hv = vacc + bias[colg];
          hv = hv > 0.f ? hv : 0.f;
          outb[off] = f2b(hv);
        } else {
          float nx = xres[off] + vacc + bias[colg];
          xres[off] = nx; outb[off] = f2b(nx);
        }
      }
    }
  }
}

// ---------------- MFMA flash attention v3 (R11, unchanged) ----------------
template<int E>
__device__ __forceinline__ bf16x8 buildP(const f32x16& p) {
  uint32_t a = pkbf(p[E + 0], p[E + 1]);
  uint32_t b = pkbf(p[E + 4], p[E + 5]);
  uint32_t c = pkbf(p[E + 2], p[E + 3]);
  uint32_t d = pkbf(p[E + 6], p[E + 7]);
  asm("v_permlane32_swap_b32 %0, %1" : "+v"(a), "+v"(b));
  asm("v_permlane32_swap_b32 %0, %1" : "+v"(c), "+v"(d));
  union { uint32_t u[4]; bf16x8 v; } r;
  r.u[0] = a; r.u[1] = c; r.u[2] = b; r.u[3] = d;
  return r.v;
}

__global__ __launch_bounds__(256) void attn_kernel(const unsigned short* __restrict__ qkv,
                                                   unsigned short* __restrict__ ob) {
  __shared__ unsigned short Kl[2][64 * 64];
  __shared__ unsigned short Vt[2][64 * 64];
  const int tid = threadIdx.x;
  const int wv = tid >> 6, ln = tid & 63;
  const int lq = ln & 31, hi = ln >> 5;
  const int qt = blockIdx.x >> 8, bh = blockIdx.x & 255;
  const int b = bh >> 4, h = bh & 15;
  const int qrow = qt * 128 + wv * 32 + lq;
  const size_t rowQ = (size_t)(b * TT + qrow) * 3072 + h * 64;

  const float cs = 0.125f * 1.44269504f;
  bf16x8 qf[4];
  #pragma unroll
  for (int t = 0; t < 4; ++t) {
    uint4 u = *(const uint4*)(qkv + rowQ + t * 16 + hi * 8);
    uint32_t w[4] = {u.x, u.y, u.z, u.w};
    union { uint32_t u4[4]; bf16x8 v; } cv;
    #pragma unroll
    for (int j = 0; j < 4; ++j) cv.u4[j] = pkbf(blo(w[j]) * cs, bhi(w[j]) * cs);
    qf[t] = cv.v;
  }

  auto stageK = [&](int i, int p) {
    #pragma unroll
    for (int r = 0; r < 2; ++r) {
      int ch = r * 256 + tid;
      int k = ch >> 3, cc = ch & 7;
      int sg = (k & 7) ^ (k >> 3);
      const unsigned short* gs = qkv + (size_t)(b * TT + i * 64 + k) * 3072 + 1024 + h * 64 + ((cc ^ sg) << 3);
      gload16(gs, &Kl[p][(size_t)(r * 256 + wv * 64) * 8]);
    }
  };
  auto loadV = [&](int i, uint4& g1, uint4& g2) {
    int cc = tid & 7, kp = tid >> 3;
    const unsigned short* gv = qkv + (size_t)(b * TT + i * 64 + kp * 2) * 3072 + 2048 + h * 64 + cc * 8;
    g1 = *(const uint4*)gv;
    g2 = *(const uint4*)(gv + 3072);
  };
  auto writeVt = [&](int p, uint4 g1, uint4 g2) {
    int cc = tid & 7, k = (tid >> 3) * 2;
    uint32_t w1[4] = {g1.x, g1.y, g1.z, g1.w}, w2[4] = {g2.x, g2.y, g2.z, g2.w};
    #pragma unroll
    for (int j = 0; j < 8; ++j) {
      int d = cc * 8 + j;
      uint32_t dw = (j & 1) ? ((w1[j >> 1] >> 16) | (w2[j >> 1] & 0xFFFF0000u))
                            : ((w1[j >> 1] & 0xFFFFu) | (w2[j >> 1] << 16));
      int sg = (d & 7) ^ (d >> 3);
      *(uint32_t*)(&Vt[p][d * 64 + (k ^ (sg << 3))]) = dw;
    }
  };

  f32x16 o0 = {}, o1 = {};
  float mrun = -3.0e38f, lsum = 0.f;

  uint4 vg1, vg2;
  stageK(0, 0);
  loadV(0, vg1, vg2);
  writeVt(0, vg1, vg2);
  asm volatile("s_waitcnt lgkmcnt(0)" ::: "memory");
  __builtin_amdgcn_s_barrier();

  for (int i = 0; i < 8; ++i) {
    const int p = i & 1;
    if (i < 7) { stageK(i + 1, p ^ 1); loadV(i + 1, vg1, vg2); }

    f32x16 s0 = {}, s1 = {};
    __builtin_amdgcn_s_setprio(1);
    #pragma unroll
    for (int t = 0; t < 4; ++t) {
      int r0 = lq, r1 = 32 + lq;
      bf16x8 a0 = *(const bf16x8*)(&Kl[p][r0 * 64 + ((((t << 1) | hi) ^ ((r0 & 7) ^ (r0 >> 3))) << 3)]);
      bf16x8 a1 = *(const bf16x8*)(&Kl[p][r1 * 64 + ((((t << 1) | hi) ^ ((r1 & 7) ^ (r1 >> 3))) << 3)]);
      s0 = __builtin_amdgcn_mfma_f32_32x32x16_bf16(a0, qf[t], s0, 0, 0, 0);
      s1 = __builtin_amdgcn_mfma_f32_32x32x16_bf16(a1, qf[t], s1, 0, 0, 0);
    }
    __builtin_amdgcn_s_setprio(0);

    float m8[8];
    #pragma unroll
    for (int r = 0; r < 8; ++r)
      m8[r] = fmaxf(fmaxf(s0[r], s0[r + 8]), fmaxf(s1[r], s1[r + 8]));
    #pragma unroll
    for (int st = 4; st > 0; st >>= 1)
      #pragma unroll
      for (int r = 0; r < st; ++r)
        m8[r] = fmaxf(m8[r], m8[r + st]);
    float mx = fmaxf(m8[0], __shfl_xor(m8[0], 32));

    if (!__all(mx - mrun <= 8.0f)) {
      float mnew = fmaxf(mrun, mx);
      float cf = ex2(mrun - mnew);
      lsum *= cf;
      #pragma unroll
      for (int r = 0; r < 16; ++r) { o0[r] *= cf; o1[r] *= cf; }
      mrun = mnew;
    }
    #pragma unroll
    for (int r = 0; r < 16; ++r) {
      s0[r] = ex2(s0[r] - mrun);
      s1[r] = ex2(s1[r] - mrun);
      lsum += s0[r] + s1[r];
    }

    bf16x8 pf0 = buildP<0>(s0);
    bf16x8 pf1 = buildP<8>(s0);
    bf16x8 pf2 = buildP<0>(s1);
    bf16x8 pf3 = buildP<8>(s1);

    if (i < 7) writeVt(p ^ 1, vg1, vg2);

    __builtin_amdgcn_s_setprio(1);
    #pragma unroll
    for (int t = 0; t < 4; ++t) {
      bf16x8 pf = (t == 0) ? pf0 : (t == 1) ? pf1 : (t == 2) ? pf2 : pf3;
      int d0 = lq, d1 = 32 + lq;
      bf16x8 v0 = *(const bf16x8*)(&Vt[p][d0 * 64 + ((((t << 1) | hi) ^ ((d0 & 7) ^ (d0 >> 3))) << 3)]);
      bf16x8 v1 = *(const bf16x8*)(&Vt[p][d1 * 64 + ((((t << 1) | hi) ^ ((d1 & 7) ^ (d1 >> 3))) << 3)]);
      o0 = __builtin_amdgcn_mfma_f32_32x32x16_bf16(v0, pf, o0, 0, 0, 0);
      o1 = __builtin_amdgcn_mfma_f32_32x32x16_bf16(v1, pf, o1, 0, 0, 0);
    }
    __builtin_amdgcn_s_setprio(0);

    asm volatile("s_waitcnt lgkmcnt(0)" ::: "memory");
    __builtin_amdgcn_sched_barrier(0);
    __builtin_amdgcn_s_barrier();
  }

  lsum += __shfl_xor(lsum, 32);
  float inv = 1.f / lsum;
  size_t orow = (size_t)(b * TT + qrow) * CC + h * 64;
  #pragma unroll
  for (int md = 0; md < 2; ++md) {
    #pragma unroll
    for (int rq = 0; rq < 4; ++rq) {
      int d0 = md * 32 + rq * 8 + hi * 4;
      float e0 = (md ? o1[rq * 4 + 0] : o0[rq * 4 + 0]) * inv;
      float e1 = (md ? o1[rq * 4 + 1] : o0[rq * 4 + 1]) * inv;
      float e2 = (md ? o1[rq * 4 + 2] : o0[rq * 4 + 2]) * inv;
      float e3 = (md ? o1[rq * 4 + 3] : o0[rq * 4 + 3]) * inv;
      uint2 st; st.x = pkbf(e0, e1); st.y = pkbf(e2, e3);
      *(uint2*)(ob + orow + d0) = st;
    }
  }
}

// ---------------- final: out[b,c] = sum_t x[b,t,c] * I[b,t] ----------------
__global__ __launch_bounds__(256) void final_kernel(const float* __restrict__ x,
                                                    const float* __restrict__ I,
                                                    float* __restrict__ out) {
  int b = blockIdx.x >> 2;
  int c = ((blockIdx.x & 3) << 8) + threadIdx.x;
  float acc = 0.f;
  const float* xp = x + (size_t)b * TT * CC + c;
  const float* Ip = I + (size_t)b * TT;
  for (int t = 0; t < TT; ++t) acc = fmaf(xp[(size_t)t * CC], Ip[t], acc);
  out[b * CC + c] = acc;
}

extern "C" void kernel_launch(void* const* d_in, const int* in_sizes, int n_in,
                              void* d_out, int out_size, void* d_ws, size_t ws_size,
                              hipStream_t stream) {
  const int*   X      = (const int*)d_in[0];
  const float* I      = (const float*)d_in[1];
  const int*   S      = (const int*)d_in[2];
  const float* emb    = (const float*)d_in[3];
  const float* pos    = (const float*)d_in[4];
  const float* qkv_w  = (const float*)d_in[5];
  const float* out_w  = (const float*)d_in[6];
  const float* ffn_w1 = (const float*)d_in[7];
  const float* ffn_b1 = (const float*)d_in[8];
  const float* ffn_w2 = (const float*)d_in[9];
  const float* ffn_b2 = (const float*)d_in[10];
  float* out = (float*)d_out;

  char* ws = (char*)d_ws;
  size_t off = 0;
  auto walloc = [&](size_t bytes) { char* p = ws + off; off += (bytes + 255) & ~(size_t)255; return p; };
  unsigned short* wqkv = (unsigned short*)walloc((size_t)LAYERS * 3 * CC * CC * 2);
  unsigned short* wo   = (unsigned short*)walloc((size_t)LAYERS * CC * CC * 2);
  unsigned short* w1   = (unsigned short*)walloc((size_t)LAYERS * CC * CC * 2);
  unsigned short* w2   = (unsigned short*)walloc((size_t)LAYERS * CC * CC * 2);
  float*          x    = (float*)walloc((size_t)MM * CC * 4);
  unsigned short* xb   = (unsigned short*)walloc((size_t)MM * CC * 2);
  unsigned short* qkvb = (unsigned short*)walloc((size_t)MM * 3 * CC * 2);
  unsigned short* obuf = (unsigned short*)walloc((size_t)MM * CC * 2);
  unsigned short* hbuf = (unsigned short*)walloc((size_t)MM * CC * 2);
  if (off > ws_size) return;

  const int nCvt = (LAYERS * 3 * CC * CC + 3 * LAYERS * CC * CC) / 4;
  cvt4_kernel<<<(nCvt + 255) / 256, 256, 0, stream>>>(qkv_w, out_w, ffn_w1, ffn_w2,
                                                      wqkv, wo, w1, w2);

  embed_kernel<<<MM, 256, 0, stream>>>(X, S, emb, pos, x, xb);

  const size_t lds256 = 2 * (256 + 128) * 32 * 2;   // 48KB
  const size_t lds128 = 2 * (128 + 128) * 32 * 2;   // 32KB
  for (int l = 0; l < LAYERS; ++l) {
    gemm8_kernel<0, 256, 6><<<(MM / 256) * (3 * CC / 128), 512, lds256, stream>>>(
        xb, wqkv + (size_t)l * 3 * CC * CC, nullptr, qkvb, nullptr, 3 * CC, 3 * CC / 128);
    attn_kernel<<<4 * 256, 256, 0, stream>>>(qkvb, obuf);
    gemm8_kernel<1, 128, 4><<<(MM / 128) * (CC / 128), 512, lds128, stream>>>(
        obuf, wo + (size_t)l * CC * CC, x, xb, nullptr, CC, CC / 128);
    gemm8_kernel<2, 128, 4><<<(MM / 128) * (CC / 128), 512, lds128, stream>>>(
        xb, w1 + (size_t)l * CC * CC, nullptr, hbuf, ffn_b1 + l * CC, CC, CC / 128);
    gemm8_kernel<3, 128, 4><<<(MM / 128) * (CC / 128), 512, lds128, stream>>>(
        hbuf, w2 + (size_t)l * CC * CC, x, xb, ffn_b2 + l * CC, CC, CC / 128);
  }

  final_kernel<<<BB * 4, 256, 0, stream>>>(x, I, out);
}

// Round 16
// 773.029 us; speedup vs baseline: 2.6534x; 2.6534x over previous
//
#include <hip/hip_runtime.h>
#include <stdint.h>

#define LAYERS 4
#define BB 16
#define TT 512
#define CC 1024
#define HH 16
#define DD 64
#define VV 32000
#define MM (BB*TT)   // 8192 rows

typedef __attribute__((ext_vector_type(8))) short bf16x8;
typedef __attribute__((ext_vector_type(4))) float f32x4;
typedef __attribute__((ext_vector_type(16))) float f32x16;

__device__ __forceinline__ unsigned short f2b(float f) {
  union { float f; unsigned int u; } v; v.f = f;
  unsigned int r = v.u + 0x7FFFu + ((v.u >> 16) & 1u);
  return (unsigned short)(r >> 16);
}
__device__ __forceinline__ float blo(unsigned int u) {
  union { unsigned int x; float f; } v; v.x = u << 16; return v.f;
}
__device__ __forceinline__ float bhi(unsigned int u) {
  union { unsigned int x; float f; } v; v.x = u & 0xFFFF0000u; return v.f;
}
__device__ __forceinline__ uint32_t pkbf(float lo, float hi) {
  uint32_t d; asm("v_cvt_pk_bf16_f32 %0, %1, %2" : "=v"(d) : "v"(lo), "v"(hi)); return d;
}
__device__ __forceinline__ float ex2(float x) {
  float r; asm("v_exp_f32 %0, %1" : "=v"(r) : "v"(x)); return r;
}
__device__ __forceinline__ void gload16(const unsigned short* g, const unsigned short* lds) {
  __builtin_amdgcn_global_load_lds((const __attribute__((address_space(1))) void*)g,
                                   (__attribute__((address_space(3))) void*)lds, 16, 0, 0);
}

// ---------------- fused weight fp32 -> bf16 (all 4 weight tensors, 1 launch) ----------------
__global__ __launch_bounds__(256) void cvt4_kernel(
    const float* __restrict__ a, const float* __restrict__ b,
    const float* __restrict__ c, const float* __restrict__ d,
    unsigned short* __restrict__ wa, unsigned short* __restrict__ wb,
    unsigned short* __restrict__ wc, unsigned short* __restrict__ wd) {
  const int nA = LAYERS * 3 * CC * CC / 4;
  const int nR = LAYERS * CC * CC / 4;
  int i = blockIdx.x * 256 + threadIdx.x;
  const float* src; unsigned short* dst; int off;
  if (i < nA)               { src = a; dst = wa; off = i; }
  else if (i < nA + nR)     { src = b; dst = wb; off = i - nA; }
  else if (i < nA + 2 * nR) { src = c; dst = wc; off = i - nA - nR; }
  else                      { src = d; dst = wd; off = i - nA - 2 * nR; }
  float4 v = ((const float4*)src)[off];
  ushort4 o; o.x = f2b(v.x); o.y = f2b(v.y); o.z = f2b(v.z); o.w = f2b(v.w);
  ((ushort4*)dst)[off] = o;
}

// ---------------- embedding: x = emb[Xm] + pos ----------------
__global__ __launch_bounds__(256) void embed_kernel(const int* __restrict__ X, const int* __restrict__ S,
    const float* __restrict__ emb, const float* __restrict__ pos,
    float* __restrict__ x, unsigned short* __restrict__ xb) {
  int bt = blockIdx.x; int tid = threadIdx.x;
  int t = bt & (TT - 1);
  int tok = S[bt] ? X[bt] : VV;
  float4 e = ((const float4*)(emb + (size_t)tok * CC))[tid];
  float4 p = ((const float4*)(pos + (size_t)t * CC))[tid];
  float4 r; r.x = e.x + p.x; r.y = e.y + p.y; r.z = e.z + p.z; r.w = e.w + p.w;
  ((float4*)(x + (size_t)bt * CC))[tid] = r;
  ushort4 ub; ub.x = f2b(r.x); ub.y = f2b(r.y); ub.z = f2b(r.z); ub.w = f2b(r.w);
  ((ushort4*)(xb + (size_t)bt * CC))[tid] = ub;
}

// ---------------- GEMM v8 (R10/R11-verified config): BK=32, double-buffer, WPE=4 ALWAYS ----------------
// LESSON (R12, R15): never raise launch_bounds' 2nd arg on a register-heavy MFMA kernel --
// hipcc silently caps VGPR below the shape's need (~110+) and spills acc to scratch
// (R15: VGPR 40, WRITE_SIZE 1 GB, MfmaUtil 5%). WPE=4 is verified: VGPR 76 (BM=256) / 36 (BM=128).
template<int EPI, int BM>
__global__ __launch_bounds__(512, 4) void gemm8_kernel(
    const unsigned short* __restrict__ A,
    const unsigned short* __restrict__ W,
    float* __restrict__ xres,
    unsigned short* __restrict__ outb,
    const float* __restrict__ bias,
    int N, int nbx) {
  constexpr int NA = BM / 128;
  constexpr int MI = BM / 64;
  constexpr int BUFS = (BM + 128) * 32;
  extern __shared__ unsigned short lds[];
  const int K = 1024;
  const int tid = threadIdx.x;
  const int wv = tid >> 6, ln = tid & 63;
  const int g = ln >> 4, rr = ln & 15;
  const int wm = wv >> 1, wn = wv & 1;

  const int nwg = gridDim.x;
  const int bid = blockIdx.x;
  const int swz = (bid & 7) * (nwg >> 3) + (bid >> 3);
  const int by = swz / nbx, bx = swz - by * nbx;
  const int brow = by * BM, bcol = bx * 128;

  const unsigned short* asrc[NA];
  #pragma unroll
  for (int rd = 0; rd < NA; ++rd) {
    int p = rd * 512 + tid;
    int row = p >> 2, gg = p & 3;
    asrc[rd] = A + (size_t)(brow + row) * K + (gg ^ ((row >> 1) & 3)) * 8;
  }
  const unsigned short* bsrc;
  {
    int row = tid >> 2, gg = tid & 3;
    bsrc = W + (size_t)(bcol + row) * K + (gg ^ ((row >> 1) & 3)) * 8;
  }

  auto stage = [&](int tile, int buf) {
    unsigned short* Aba = lds + buf * BUFS;
    unsigned short* Bba = Aba + BM * 32;
    int ko = tile * 32;
    #pragma unroll
    for (int rd = 0; rd < NA; ++rd)
      gload16(asrc[rd] + ko, Aba + (rd * 512 + wv * 64) * 8);
    gload16(bsrc + ko, Bba + (wv * 64) * 8);
  };

  f32x4 acc[MI][4];
  #pragma unroll
  for (int i = 0; i < MI; ++i)
    #pragma unroll
    for (int j = 0; j < 4; ++j)
      acc[i][j] = (f32x4){0.f, 0.f, 0.f, 0.f};

  stage(0, 0);

  const int chx = (g ^ ((rr >> 1) & 3)) * 8;
  for (int t = 0; t < 32; ++t) {
    if (t < 31) {
      stage(t + 1, (t + 1) & 1);
      asm volatile("s_waitcnt vmcnt(%0)" :: "i"(NA + 1) : "memory");
    } else {
      asm volatile("s_waitcnt vmcnt(0)" ::: "memory");
    }
    __builtin_amdgcn_s_barrier();
    __builtin_amdgcn_sched_barrier(0);

    const unsigned short* Aba = lds + (t & 1) * BUFS;
    const unsigned short* Bba = Aba + BM * 32;
    bf16x8 av[MI], bv[4];
    #pragma unroll
    for (int i = 0; i < MI; ++i)
      av[i] = *(const bf16x8*)(Aba + (wm * (BM / 4) + i * 16 + rr) * 32 + chx);
    #pragma unroll
    for (int j = 0; j < 4; ++j)
      bv[j] = *(const bf16x8*)(Bba + (wn * 64 + j * 16 + rr) * 32 + chx);

    __builtin_amdgcn_s_setprio(1);
    #pragma unroll
    for (int i = 0; i < MI; ++i)
      #pragma unroll
      for (int j = 0; j < 4; ++j)
        acc[i][j] = __builtin_amdgcn_mfma_f32_16x16x32_bf16(av[i], bv[j], acc[i][j], 0, 0, 0);
    __builtin_amdgcn_s_setprio(0);
    __builtin_amdgcn_sched_barrier(0);
    __builtin_amdgcn_s_barrier();
  }

  #pragma unroll
  for (int i = 0; i < MI; ++i) {
    #pragma unroll
    for (int j = 0; j < 4; ++j) {
      #pragma unroll
      for (int q = 0; q < 4; ++q) {
        int rowg = brow + wm * (BM / 4) + i * 16 + g * 4 + q;
        int colg = bcol + wn * 64 + j * 16 + rr;
        size_t off = (size_t)rowg * N + colg;
        float vacc = acc[i][j][q];
        if (EPI == 0) {
          outb[off] = f2b(vacc);
        } else if (EPI == 1) {
          float nx = xres[off] + vacc;
          xres[off] = nx; outb[off] = f2b(nx);
        } else if (EPI == 2) {
          float hv = vacc + bias[colg];
          hv = hv > 0.f ? hv : 0.f;
          outb[off] = f2b(hv);
        } else {
          float nx = xres[off] + vacc + bias[colg];
          xres[off] = nx; outb[off] = f2b(nx);
        }
      }
    }
  }
}

// ---------------- MFMA flash attention v3 (R11, unchanged) ----------------
template<int E>
__device__ __forceinline__ bf16x8 buildP(const f32x16& p) {
  uint32_t a = pkbf(p[E + 0], p[E + 1]);
  uint32_t b = pkbf(p[E + 4], p[E + 5]);
  uint32_t c = pkbf(p[E + 2], p[E + 3]);
  uint32_t d = pkbf(p[E + 6], p[E + 7]);
  asm("v_permlane32_swap_b32 %0, %1" : "+v"(a), "+v"(b));
  asm("v_permlane32_swap_b32 %0, %1" : "+v"(c), "+v"(d));
  union { uint32_t u[4]; bf16x8 v; } r;
  r.u[0] = a; r.u[1] = c; r.u[2] = b; r.u[3] = d;
  return r.v;
}

__global__ __launch_bounds__(256) void attn_kernel(const unsigned short* __restrict__ qkv,
                                                   unsigned short* __restrict__ ob) {
  __shared__ unsigned short Kl[2][64 * 64];
  __shared__ unsigned short Vt[2][64 * 64];
  const int tid = threadIdx.x;
  const int wv = tid >> 6, ln = tid & 63;
  const int lq = ln & 31, hi = ln >> 5;
  const int qt = blockIdx.x >> 8, bh = blockIdx.x & 255;
  const int b = bh >> 4, h = bh & 15;
  const int qrow = qt * 128 + wv * 32 + lq;
  const size_t rowQ = (size_t)(b * TT + qrow) * 3072 + h * 64;

  const float cs = 0.125f * 1.44269504f;
  bf16x8 qf[4];
  #pragma unroll
  for (int t = 0; t < 4; ++t) {
    uint4 u = *(const uint4*)(qkv + rowQ + t * 16 + hi * 8);
    uint32_t w[4] = {u.x, u.y, u.z, u.w};
    union { uint32_t u4[4]; bf16x8 v; } cv;
    #pragma unroll
    for (int j = 0; j < 4; ++j) cv.u4[j] = pkbf(blo(w[j]) * cs, bhi(w[j]) * cs);
    qf[t] = cv.v;
  }

  auto stageK = [&](int i, int p) {
    #pragma unroll
    for (int r = 0; r < 2; ++r) {
      int ch = r * 256 + tid;
      int k = ch >> 3, cc = ch & 7;
      int sg = (k & 7) ^ (k >> 3);
      const unsigned short* gs = qkv + (size_t)(b * TT + i * 64 + k) * 3072 + 1024 + h * 64 + ((cc ^ sg) << 3);
      gload16(gs, &Kl[p][(size_t)(r * 256 + wv * 64) * 8]);
    }
  };
  auto loadV = [&](int i, uint4& g1, uint4& g2) {
    int cc = tid & 7, kp = tid >> 3;
    const unsigned short* gv = qkv + (size_t)(b * TT + i * 64 + kp * 2) * 3072 + 2048 + h * 64 + cc * 8;
    g1 = *(const uint4*)gv;
    g2 = *(const uint4*)(gv + 3072);
  };
  auto writeVt = [&](int p, uint4 g1, uint4 g2) {
    int cc = tid & 7, k = (tid >> 3) * 2;
    uint32_t w1[4] = {g1.x, g1.y, g1.z, g1.w}, w2[4] = {g2.x, g2.y, g2.z, g2.w};
    #pragma unroll
    for (int j = 0; j < 8; ++j) {
      int d = cc * 8 + j;
      uint32_t dw = (j & 1) ? ((w1[j >> 1] >> 16) | (w2[j >> 1] & 0xFFFF0000u))
                            : ((w1[j >> 1] & 0xFFFFu) | (w2[j >> 1] << 16));
      int sg = (d & 7) ^ (d >> 3);
      *(uint32_t*)(&Vt[p][d * 64 + (k ^ (sg << 3))]) = dw;
    }
  };

  f32x16 o0 = {}, o1 = {};
  float mrun = -3.0e38f, lsum = 0.f;

  uint4 vg1, vg2;
  stageK(0, 0);
  loadV(0, vg1, vg2);
  writeVt(0, vg1, vg2);
  asm volatile("s_waitcnt lgkmcnt(0)" ::: "memory");
  __builtin_amdgcn_s_barrier();

  for (int i = 0; i < 8; ++i) {
    const int p = i & 1;
    if (i < 7) { stageK(i + 1, p ^ 1); loadV(i + 1, vg1, vg2); }

    f32x16 s0 = {}, s1 = {};
    __builtin_amdgcn_s_setprio(1);
    #pragma unroll
    for (int t = 0; t < 4; ++t) {
      int r0 = lq, r1 = 32 + lq;
      bf16x8 a0 = *(const bf16x8*)(&Kl[p][r0 * 64 + ((((t << 1) | hi) ^ ((r0 & 7) ^ (r0 >> 3))) << 3)]);
      bf16x8 a1 = *(const bf16x8*)(&Kl[p][r1 * 64 + ((((t << 1) | hi) ^ ((r1 & 7) ^ (r1 >> 3))) << 3)]);
      s0 = __builtin_amdgcn_mfma_f32_32x32x16_bf16(a0, qf[t], s0, 0, 0, 0);
      s1 = __builtin_amdgcn_mfma_f32_32x32x16_bf16(a1, qf[t], s1, 0, 0, 0);
    }
    __builtin_amdgcn_s_setprio(0);

    float m8[8];
    #pragma unroll
    for (int r = 0; r < 8; ++r)
      m8[r] = fmaxf(fmaxf(s0[r], s0[r + 8]), fmaxf(s1[r], s1[r + 8]));
    #pragma unroll
    for (int st = 4; st > 0; st >>= 1)
      #pragma unroll
      for (int r = 0; r < st; ++r)
        m8[r] = fmaxf(m8[r], m8[r + st]);
    float mx = fmaxf(m8[0], __shfl_xor(m8[0], 32));

    if (!__all(mx - mrun <= 8.0f)) {
      float mnew = fmaxf(mrun, mx);
      float cf = ex2(mrun - mnew);
      lsum *= cf;
      #pragma unroll
      for (int r = 0; r < 16; ++r) { o0[r] *= cf; o1[r] *= cf; }
      mrun = mnew;
    }
    #pragma unroll
    for (int r = 0; r < 16; ++r) {
      s0[r] = ex2(s0[r] - mrun);
      s1[r] = ex2(s1[r] - mrun);
      lsum += s0[r] + s1[r];
    }

    bf16x8 pf0 = buildP<0>(s0);
    bf16x8 pf1 = buildP<8>(s0);
    bf16x8 pf2 = buildP<0>(s1);
    bf16x8 pf3 = buildP<8>(s1);

    if (i < 7) writeVt(p ^ 1, vg1, vg2);

    __builtin_amdgcn_s_setprio(1);
    #pragma unroll
    for (int t = 0; t < 4; ++t) {
      bf16x8 pf = (t == 0) ? pf0 : (t == 1) ? pf1 : (t == 2) ? pf2 : pf3;
      int d0 = lq, d1 = 32 + lq;
      bf16x8 v0 = *(const bf16x8*)(&Vt[p][d0 * 64 + ((((t << 1) | hi) ^ ((d0 & 7) ^ (d0 >> 3))) << 3)]);
      bf16x8 v1 = *(const bf16x8*)(&Vt[p][d1 * 64 + ((((t << 1) | hi) ^ ((d1 & 7) ^ (d1 >> 3))) << 3)]);
      o0 = __builtin_amdgcn_mfma_f32_32x32x16_bf16(v0, pf, o0, 0, 0, 0);
      o1 = __builtin_amdgcn_mfma_f32_32x32x16_bf16(v1, pf, o1, 0, 0, 0);
    }
    __builtin_amdgcn_s_setprio(0);

    asm volatile("s_waitcnt lgkmcnt(0)" ::: "memory");
    __builtin_amdgcn_sched_barrier(0);
    __builtin_amdgcn_s_barrier();
  }

  lsum += __shfl_xor(lsum, 32);
  float inv = 1.f / lsum;
  size_t orow = (size_t)(b * TT + qrow) * CC + h * 64;
  #pragma unroll
  for (int md = 0; md < 2; ++md) {
    #pragma unroll
    for (int rq = 0; rq < 4; ++rq) {
      int d0 = md * 32 + rq * 8 + hi * 4;
      float e0 = (md ? o1[rq * 4 + 0] : o0[rq * 4 + 0]) * inv;
      float e1 = (md ? o1[rq * 4 + 1] : o0[rq * 4 + 1]) * inv;
      float e2 = (md ? o1[rq * 4 + 2] : o0[rq * 4 + 2]) * inv;
      float e3 = (md ? o1[rq * 4 + 3] : o0[rq * 4 + 3]) * inv;
      uint2 st; st.x = pkbf(e0, e1); st.y = pkbf(e2, e3);
      *(uint2*)(ob + orow + d0) = st;
    }
  }
}

// ---------------- final: out[b,c] = sum_t x[b,t,c] * I[b,t] ----------------
__global__ __launch_bounds__(256) void final_kernel(const float* __restrict__ x,
                                                    const float* __restrict__ I,
                                                    float* __restrict__ out) {
  int b = blockIdx.x >> 2;
  int c = ((blockIdx.x & 3) << 8) + threadIdx.x;
  float acc = 0.f;
  const float* xp = x + (size_t)b * TT * CC + c;
  const float* Ip = I + (size_t)b * TT;
  for (int t = 0; t < TT; ++t) acc = fmaf(xp[(size_t)t * CC], Ip[t], acc);
  out[b * CC + c] = acc;
}

extern "C" void kernel_launch(void* const* d_in, const int* in_sizes, int n_in,
                              void* d_out, int out_size, void* d_ws, size_t ws_size,
                              hipStream_t stream) {
  const int*   X      = (const int*)d_in[0];
  const float* I      = (const float*)d_in[1];
  const int*   S      = (const int*)d_in[2];
  const float* emb    = (const float*)d_in[3];
  const float* pos    = (const float*)d_in[4];
  const float* qkv_w  = (const float*)d_in[5];
  const float* out_w  = (const float*)d_in[6];
  const float* ffn_w1 = (const float*)d_in[7];
  const float* ffn_b1 = (const float*)d_in[8];
  const float* ffn_w2 = (const float*)d_in[9];
  const float* ffn_b2 = (const float*)d_in[10];
  float* out = (float*)d_out;

  char* ws = (char*)d_ws;
  size_t off = 0;
  auto walloc = [&](size_t bytes) { char* p = ws + off; off += (bytes + 255) & ~(size_t)255; return p; };
  unsigned short* wqkv = (unsigned short*)walloc((size_t)LAYERS * 3 * CC * CC * 2);
  unsigned short* wo   = (unsigned short*)walloc((size_t)LAYERS * CC * CC * 2);
  unsigned short* w1   = (unsigned short*)walloc((size_t)LAYERS * CC * CC * 2);
  unsigned short* w2   = (unsigned short*)walloc((size_t)LAYERS * CC * CC * 2);
  float*          x    = (float*)walloc((size_t)MM * CC * 4);
  unsigned short* xb   = (unsigned short*)walloc((size_t)MM * CC * 2);
  unsigned short* qkvb = (unsigned short*)walloc((size_t)MM * 3 * CC * 2);
  unsigned short* obuf = (unsigned short*)walloc((size_t)MM * CC * 2);
  unsigned short* hbuf = (unsigned short*)walloc((size_t)MM * CC * 2);
  if (off > ws_size) return;

  const int nCvt = (LAYERS * 3 * CC * CC + 3 * LAYERS * CC * CC) / 4;
  cvt4_kernel<<<(nCvt + 255) / 256, 256, 0, stream>>>(qkv_w, out_w, ffn_w1, ffn_w2,
                                                      wqkv, wo, w1, w2);

  embed_kernel<<<MM, 256, 0, stream>>>(X, S, emb, pos, x, xb);

  const size_t lds256 = 2 * (256 + 128) * 32 * 2;   // 48KB
  const size_t lds128 = 2 * (128 + 128) * 32 * 2;   // 32KB
  for (int l = 0; l < LAYERS; ++l) {
    gemm8_kernel<0, 256><<<(MM / 256) * (3 * CC / 128), 512, lds256, stream>>>(
        xb, wqkv + (size_t)l * 3 * CC * CC, nullptr, qkvb, nullptr, 3 * CC, 3 * CC / 128);
    attn_kernel<<<4 * 256, 256, 0, stream>>>(qkvb, obuf);
    gemm8_kernel<1, 128><<<(MM / 128) * (CC / 128), 512, lds128, stream>>>(
        obuf, wo + (size_t)l * CC * CC, x, xb, nullptr, CC, CC / 128);
    gemm8_kernel<2, 128><<<(MM / 128) * (CC / 128), 512, lds128, stream>>>(
        xb, w1 + (size_t)l * CC * CC, nullptr, hbuf, ffn_b1 + l * CC, CC, CC / 128);
    gemm8_kernel<3, 128><<<(MM / 128) * (CC / 128), 512, lds128, stream>>>(
        hbuf, w2 + (size_t)l * CC * CC, x, xb, ffn_b2 + l * CC, CC, CC / 128);
  }

  final_kernel<<<BB * 4, 256, 0, stream>>>(x, I, out);
}